// Round 1
// baseline (82.479 us; speedup 1.0000x reference)
//
#include <hip/hip_runtime.h>

// Problem: loss = BCE_with_logits(pred, psi) + 10 * mean_valid((d_i - d_j)^2)
// where d = pred - logit(clamp(psi, eps, 1-eps)), valid = |psi_i - psi_j| >= 0.05.
// N = 8192. Output: single fp32 scalar.

constexpr float DPSI_T   = 0.05f;
constexpr float LOGIT_EPS = 1e-7f;

__device__ __forceinline__ float logit_f(float p) {
    p = fminf(fmaxf(p, LOGIT_EPS), 1.0f - LOGIT_EPS);
    return logf(p) - log1pf(-p);
}

// Block (bx,by): rows [bx*256, bx*256+256) x cols [by*256, by*256+256).
// Column tile (psi_j, d_j) staged in LDS as float2; all 64 lanes read the same
// element each inner iteration -> LDS broadcast (conflict-free).
__global__ __launch_bounds__(256) void pair_kernel(const float* __restrict__ pred,
                                                   const float* __restrict__ psi,
                                                   float* __restrict__ part_sum,
                                                   unsigned int* __restrict__ part_cnt,
                                                   int n) {
    __shared__ float2 tile[256];
    const int tid = threadIdx.x;
    const float NANF = __int_as_float(0x7fc00000);

    // Stage column tile: d_j computed on the fly (redundant across row-blocks,
    // but only 2 logf per element -- negligible).
    int j = blockIdx.y * 256 + tid;
    if (j < n) {
        float pj = psi[j];
        tile[tid] = make_float2(pj, pred[j] - logit_f(pj));
    } else {
        tile[tid] = make_float2(NANF, 0.0f);  // NaN psi -> never valid
    }

    // Row data in registers.
    int i = blockIdx.x * 256 + tid;
    float psi_i, d_i;
    if (i < n) {
        psi_i = psi[i];
        d_i   = pred[i] - logit_f(psi_i);
    } else {
        psi_i = NANF;
        d_i   = 0.0f;
    }
    __syncthreads();

    float sum = 0.0f;
    unsigned int cnt = 0;
    #pragma unroll 8
    for (int k = 0; k < 256; ++k) {
        float2 t   = tile[k];
        float dpsi = psi_i - t.x;
        bool valid = fabsf(dpsi) >= DPSI_T;     // NaN compares -> false
        float dd   = d_i - t.y;
        float ddm  = valid ? dd : 0.0f;          // mask BEFORE squaring (NaN-safe)
        sum = fmaf(ddm, ddm, sum);
        cnt += valid ? 1u : 0u;
    }

    // Block reduce: wave shuffle then cross-wave LDS.
    for (int off = 32; off; off >>= 1) {
        sum += __shfl_down(sum, off);
        cnt += __shfl_down(cnt, off);
    }
    __shared__ float wsum[4];
    __shared__ unsigned int wcnt[4];
    int wave = tid >> 6, lane = tid & 63;
    if (lane == 0) { wsum[wave] = sum; wcnt[wave] = cnt; }
    __syncthreads();
    if (tid == 0) {
        float s = wsum[0] + wsum[1] + wsum[2] + wsum[3];
        unsigned int c = wcnt[0] + wcnt[1] + wcnt[2] + wcnt[3];
        int slot = blockIdx.x * gridDim.y + blockIdx.y;
        part_sum[slot] = s;
        part_cnt[slot] = c;
    }
}

// One block: BCE over n elements + reduce per-block partials + finalize.
__global__ __launch_bounds__(256) void finalize_kernel(const float* __restrict__ pred,
                                                       const float* __restrict__ psi,
                                                       const int* __restrict__ flag,
                                                       const float* __restrict__ part_sum,
                                                       const unsigned int* __restrict__ part_cnt,
                                                       int nparts,
                                                       float* __restrict__ out,
                                                       int n) {
    const int tid = threadIdx.x;

    float bce = 0.0f;
    for (int i = tid; i < n; i += 256) {
        float x = pred[i], t = psi[i];
        bce += fmaxf(x, 0.0f) - x * t + log1pf(expf(-fabsf(x)));
    }
    float s = 0.0f;
    unsigned long long c = 0;
    for (int p = tid; p < nparts; p += 256) {
        s += part_sum[p];
        c += (unsigned long long)part_cnt[p];
    }

    for (int off = 32; off; off >>= 1) {
        bce += __shfl_down(bce, off);
        s   += __shfl_down(s, off);
        c   += __shfl_down(c, off);
    }
    __shared__ float b4[4], s4[4];
    __shared__ unsigned long long c4[4];
    int wave = tid >> 6, lane = tid & 63;
    if (lane == 0) { b4[wave] = bce; s4[wave] = s; c4[wave] = c; }
    __syncthreads();
    if (tid == 0) {
        float bce_total = (b4[0] + b4[1] + b4[2] + b4[3]) / (float)n;
        float s_total   = s4[0] + s4[1] + s4[2] + s4[3];
        unsigned long long c_total = c4[0] + c4[1] + c4[2] + c4[3];
        float loss = bce_total;
        if (flag[0] == 0 && c_total > 0) {
            loss += 10.0f * (s_total / (float)c_total);
        }
        out[0] = loss;
    }
}

extern "C" void kernel_launch(void* const* d_in, const int* in_sizes, int n_in,
                              void* d_out, int out_size, void* d_ws, size_t ws_size,
                              hipStream_t stream) {
    const float* pred = (const float*)d_in[0];
    const float* psi  = (const float*)d_in[1];
    const int*   flag = (const int*)d_in[2];
    float* out = (float*)d_out;
    int n = in_sizes[0];

    int nb = (n + 255) / 256;            // 32 for N=8192
    int nparts = nb * nb;                // 1024 -> 8 KB of workspace
    float* part_sum        = (float*)d_ws;
    unsigned int* part_cnt = (unsigned int*)((char*)d_ws + (size_t)nparts * sizeof(float));

    dim3 grid(nb, nb);
    pair_kernel<<<grid, 256, 0, stream>>>(pred, psi, part_sum, part_cnt, n);
    finalize_kernel<<<1, 256, 0, stream>>>(pred, psi, flag, part_sum, part_cnt, nparts, out, n);
}